// Round 5
// baseline (1828.490 us; speedup 1.0000x reference)
//
#include <hip/hip_runtime.h>

#define NN 20000
#define NE 640000
#define CC 128
#define HH 8
#define GG 50
#define FF 128
#define LL 3
#define TE 128   // edges per tile in k_edge

typedef unsigned short u16;
typedef __attribute__((ext_vector_type(8))) short bf16x8;   // 8 bf16 = 4 VGPRs
typedef __attribute__((ext_vector_type(4))) float f32x4;

__device__ __forceinline__ u16 f2bf(float f) {
    union { float f; unsigned int i; } x; x.f = f;
    unsigned int r = x.i + 0x7fffu + ((x.i >> 16) & 1u);
    return (u16)(r >> 16);
}
// ShiftedSoftplus: softplus(x)-log2 via HW exp/log; |err| ~1e-7, far below bf16 noise
__device__ __forceinline__ float sspf(float x) {
    return fmaxf(x, 0.0f) + __logf(1.0f + __expf(-fabsf(x))) - 0.69314718055994531f;
}

// ---------------- CSR build (sort edges by dst) ----------------
__global__ void k_zero(int* __restrict__ c, int n) {
    int i = blockIdx.x * 256 + threadIdx.x;
    if (i < n) c[i] = 0;
}

__global__ void k_zerof(float* __restrict__ c, int n) {
    int i = blockIdx.x * 256 + threadIdx.x;
    if (i < n) c[i] = 0.0f;
}

__global__ void k_hist(const int* __restrict__ ei, int* __restrict__ c) {
    int e = blockIdx.x * 256 + threadIdx.x;
    if (e < NE) atomicAdd(&c[ei[NE + e]], 1);
}

__global__ __launch_bounds__(1024) void k_scan(const int* __restrict__ cnt,
                                               int* __restrict__ rowptr,
                                               int* __restrict__ cursor) {
    __shared__ int sums[1024];
    const int t = threadIdx.x;
    int local[20];
    int base = t * 20;
    int s = 0;
    #pragma unroll
    for (int i = 0; i < 20; ++i) {
        int idx = base + i;
        int v = (idx < NN) ? cnt[idx] : 0;
        local[i] = s; s += v;
    }
    sums[t] = s;
    __syncthreads();
    for (int off = 1; off < 1024; off <<= 1) {
        int v = (t >= off) ? sums[t - off] : 0;
        __syncthreads();
        sums[t] += v;
        __syncthreads();
    }
    int excl = (t == 0) ? 0 : sums[t - 1];
    #pragma unroll
    for (int i = 0; i < 20; ++i) {
        int idx = base + i;
        if (idx < NN) { int r = excl + local[i]; rowptr[idx] = r; cursor[idx] = r; }
    }
    if (t == 1023) rowptr[NN] = sums[1023];
}

__global__ void k_scatter(const int* __restrict__ ei, int* __restrict__ cursor,
                          int* __restrict__ srcp, int* __restrict__ dstp) {
    int e = blockIdx.x * 256 + threadIdx.x;
    if (e >= NE) return;
    int s = ei[e], d = ei[NE + e];
    int pp = atomicAdd(&cursor[d], 1);
    srcp[pp] = s; dstp[pp] = d;
}

__global__ void k_hinit(const int* __restrict__ z, const float* __restrict__ emb,
                        float* __restrict__ h) {
    int i = blockIdx.x * 256 + threadIdx.x;
    if (i < NN * CC) h[i] = emb[z[i >> 7] * CC + (i & 127)];
}

// ---------------- weight prep: transpose + bf16 convert (once per call) ----------
__global__ void k_prep(const float* __restrict__ w1, const float* __restrict__ w2,
                       const float* __restrict__ we,
                       u16* __restrict__ w1tg, u16* __restrict__ w2tg,
                       u16* __restrict__ wetg) {
    int i = blockIdx.x * 256 + threadIdx.x;
    if (i < LL * 128 * 64) {
        int l = i / (128 * 64); int r = i % (128 * 64); int c = r >> 6, k = r & 63;
        float v = (k < GG) ? w1[(l * GG + k) * FF + c] : 0.0f;
        w1tg[i] = f2bf(v);
    }
    if (i < LL * 128 * 128) {
        int l = i / (128 * 128); int r = i % (128 * 128); int c = r >> 7, k = r & 127;
        w2tg[i] = f2bf(w2[(size_t)(l * FF + k) * FF + c]);
        wetg[i] = f2bf(we[(size_t)(l * FF + k) * CC + c]);
    }
}

// ---------------- fused q/k/v/skip node GEMM: stage h-tile once, 4 weights ------
__global__ __launch_bounds__(256) void k_gemm_qkvs(
    const float* __restrict__ A,
    const float* __restrict__ w0, const float* __restrict__ w1,
    const float* __restrict__ w2, const float* __restrict__ w3,
    const float* __restrict__ c0p, const float* __restrict__ c1p,
    const float* __restrict__ c2p, const float* __restrict__ c3p,
    float* __restrict__ o0, float* __restrict__ o1,
    float* __restrict__ o2, float* __restrict__ o3, int nrows)
{
    __shared__ __align__(16) float aT[128 * 66];
    __shared__ __align__(16) float wT[128 * 36];
    const int t = threadIdx.x;
    const int n0 = blockIdx.x * 64;
    for (int idx = t; idx < 64 * 128; idx += 256) {
        int i = idx >> 7, kx = idx & 127;
        int n = n0 + i;
        aT[kx * 66 + i] = (n < nrows) ? A[(size_t)n * 128 + kx] : 0.0f;
    }
    const int tx = t & 15, ty = t >> 4, e0 = ty * 4;
    const float* WW[4] = { w0, w1, w2, w3 };
    const float* BB[4] = { c0p, c1p, c2p, c3p };
    float*       OO[4] = { o0, o1, o2, o3 };
    #pragma unroll
    for (int m = 0; m < 4; ++m) {
        const float* __restrict__ W = WW[m];
        float acc[4][8];
        #pragma unroll
        for (int i = 0; i < 4; ++i)
        #pragma unroll
        for (int j = 0; j < 8; ++j) acc[i][j] = 0.0f;
        for (int k0 = 0; k0 < 128; k0 += 32) {
            __syncthreads();
            for (int idx = t; idx < 32 * 128; idx += 256) {
                int kx = idx >> 7, c = idx & 127;
                wT[c * 36 + kx] = W[(size_t)(k0 + kx) * 128 + c];
            }
            __syncthreads();
            #pragma unroll 2
            for (int kk = 0; kk < 32; kk += 4) {
                float a[4][4];
                #pragma unroll
                for (int dk = 0; dk < 4; ++dk)
                #pragma unroll
                for (int i = 0; i < 4; ++i) a[dk][i] = aT[(k0 + kk + dk) * 66 + e0 + i];
                #pragma unroll
                for (int j = 0; j < 8; ++j) {
                    const float4 b = *(const float4*)&wT[(tx + 16 * j) * 36 + kk];
                    const float bb[4] = { b.x, b.y, b.z, b.w };
                    #pragma unroll
                    for (int dk = 0; dk < 4; ++dk)
                    #pragma unroll
                    for (int i = 0; i < 4; ++i) acc[i][j] = fmaf(a[dk][i], bb[dk], acc[i][j]);
                }
            }
        }
        #pragma unroll
        for (int j = 0; j < 8; ++j) {
            int c = tx + 16 * j;
            float bb = BB[m][c];
            #pragma unroll
            for (int i = 0; i < 4; ++i) {
                int n = n0 + e0 + i;
                if (n < nrows) OO[m][(size_t)n * 128 + c] = acc[i][j] + bb;
            }
        }
    }
}

// ---------------- fused normalize+skip+ssp -> GEMM(wl) -> h += ------------------
__global__ __launch_bounds__(256) void k_gemm_update(
    const float* __restrict__ num, const float* __restrict__ den,
    const float* __restrict__ skip,
    const float* __restrict__ W, const float* __restrict__ Bias,
    float* __restrict__ h, int nrows)
{
    __shared__ __align__(16) float aT[128 * 66];
    __shared__ __align__(16) float wT[128 * 36];
    const int t = threadIdx.x;
    const int n0 = blockIdx.x * 64;
    for (int idx = t; idx < 64 * 128; idx += 256) {
        int i = idx >> 7, kx = idx & 127;
        int n = n0 + i;
        float val = 0.0f;
        if (n < nrows) {
            float r = num[(size_t)n * 128 + kx] / (den[n * HH + (kx >> 4)] + 1e-16f)
                    + skip[(size_t)n * 128 + kx];
            val = sspf(r);
        }
        aT[kx * 66 + i] = val;
    }
    const int tx = t & 15, ty = t >> 4, e0 = ty * 4;
    float acc[4][8];
    #pragma unroll
    for (int i = 0; i < 4; ++i)
    #pragma unroll
    for (int j = 0; j < 8; ++j) acc[i][j] = 0.0f;
    for (int k0 = 0; k0 < 128; k0 += 32) {
        __syncthreads();
        for (int idx = t; idx < 32 * 128; idx += 256) {
            int kx = idx >> 7, c = idx & 127;
            wT[c * 36 + kx] = W[(size_t)(k0 + kx) * 128 + c];
        }
        __syncthreads();
        #pragma unroll 2
        for (int kk = 0; kk < 32; kk += 4) {
            float a[4][4];
            #pragma unroll
            for (int dk = 0; dk < 4; ++dk)
            #pragma unroll
            for (int i = 0; i < 4; ++i) a[dk][i] = aT[(k0 + kk + dk) * 66 + e0 + i];
            #pragma unroll
            for (int j = 0; j < 8; ++j) {
                const float4 b = *(const float4*)&wT[(tx + 16 * j) * 36 + kk];
                const float bb[4] = { b.x, b.y, b.z, b.w };
                #pragma unroll
                for (int dk = 0; dk < 4; ++dk)
                #pragma unroll
                for (int i = 0; i < 4; ++i) acc[i][j] = fmaf(a[dk][i], bb[dk], acc[i][j]);
            }
        }
    }
    #pragma unroll
    for (int j = 0; j < 8; ++j) {
        int c = tx + 16 * j;
        float bb = Bias[c];
        #pragma unroll
        for (int i = 0; i < 4; ++i) {
            int n = n0 + e0 + i;
            if (n < nrows) h[(size_t)n * 128 + c] += acc[i][j] + bb;
        }
    }
}

// ---------------- persistent MFMA edge pipeline ----------------
// 16 waves (1024 thr). Wave w: wr=w>>2 owns c-rows [wr*32,wr*32+32),
// wc=w&3 owns edge-cols [wc*32, wc*32+32). All GEMMs computed transposed:
// C^T[c][r] = W^T[c][k] * X^T[k][r], MFMA 16x16x32_bf16.
// q/k/v gathers are issued at tile start (prefetch) and consumed after GEMM3.
__global__ __launch_bounds__(1024, 4) void k_edge(
    const int* __restrict__ srcp, const int* __restrict__ dstp,
    const float* __restrict__ pos,
    const u16* __restrict__ w1tg, const u16* __restrict__ w2tg, const u16* __restrict__ wetg,
    const float* __restrict__ b1, const float* __restrict__ b2, const float* __restrict__ be,
    const float* __restrict__ qn, const float* __restrict__ kn, const float* __restrict__ vn,
    float* __restrict__ num, float* __restrict__ den, int ntiles)
{
    __shared__ __align__(16) short w1T[128 * 72];    // [c][k64]  row 144B
    __shared__ __align__(16) short w2T[128 * 136];   // [c][k128] row 272B
    __shared__ __align__(16) short weT[128 * 136];
    __shared__ __align__(16) short a2[128 * 136];    // attr / act1 / f32 w*v (c<64) + w(h<4)
    __shared__ __align__(16) short e2[128 * 136];    // act2(e) / f32 w*v (c>=64) + w(h>=4)
    __shared__ float dbuf[128];
    __shared__ int sls[128], dls[128];

    const int t = threadIdx.x;
    const int lane = t & 63;
    const int w = t >> 6;
    const int wr = w >> 2, wc = w & 3;
    const int tx = lane & 15, tg = lane >> 4;

    // ---- stage weights once (bf16, transposed rows contiguous) ----
    for (int idx = t; idx < 128 * 8; idx += 1024) {
        int c = idx >> 3, pp = idx & 7;
        *(float4*)&w1T[c * 72 + pp * 8] = *(const float4*)&w1tg[c * 64 + pp * 8];
    }
    for (int idx = t; idx < 128 * 16; idx += 1024) {
        int c = idx >> 4, pp = idx & 15;
        *(float4*)&w2T[c * 136 + pp * 8] = *(const float4*)&w2tg[c * 128 + pp * 8];
        *(float4*)&weT[c * 136 + pp * 8] = *(const float4*)&wetg[c * 128 + pp * 8];
    }
    // per-lane bias registers for the c-rows this lane owns
    float b1v[8], b2v[8], bev[8];
    #pragma unroll
    for (int mt = 0; mt < 2; ++mt)
        #pragma unroll
        for (int q = 0; q < 4; ++q) {
            int c = wr * 32 + mt * 16 + tg * 4 + q;
            b1v[mt * 4 + q] = b1[c]; b2v[mt * 4 + q] = b2[c]; bev[mt * 4 + q] = be[c];
        }

    float* a2f = (float*)a2;   // [r][68] f32 view
    float* e2f = (float*)e2;

    const float STEP = 10.0f / 49.0f;
    const float COEF = -0.5f / (STEP * STEP);
    const f32x4 zf4 = { 0.0f, 0.0f, 0.0f, 0.0f };

    for (int tile = blockIdx.x; tile < ntiles; tile += gridDim.x) {
        __syncthreads();   // previous tile fully done (walk reads dls, a2f/e2f)
        if (t < TE) {
            int s = tile * TE + t;
            int a = srcp[s], b = dstp[s];
            sls[t] = a; dls[t] = b;
            float dx = pos[b * 3 + 0] - pos[a * 3 + 0];
            float dy = pos[b * 3 + 1] - pos[a * 3 + 1];
            float dz = pos[b * 3 + 2] - pos[a * 3 + 2];
            dbuf[t] = sqrtf(dx * dx + dy * dy + dz * dz + 1e-12f);
        }
        __syncthreads();

        // ---- prefetch q/k/v gathers for the epilogue (consumed after GEMM3) ----
        int rr2[2], sn2[2], dn2[2];
        #pragma unroll
        for (int nt = 0; nt < 2; ++nt) {
            rr2[nt] = wc * 32 + nt * 16 + tx;
            sn2[nt] = sls[rr2[nt]];
            dn2[nt] = dls[rr2[nt]];
        }
        float4 pq[2][2], pk[2][2], pv[2][2];
        #pragma unroll
        for (int mt = 0; mt < 2; ++mt) {
            int c0 = wr * 32 + mt * 16 + tg * 4;
            #pragma unroll
            for (int nt = 0; nt < 2; ++nt) {
                pq[mt][nt] = *(const float4*)&qn[(size_t)dn2[nt] * CC + c0];
                pk[mt][nt] = *(const float4*)&kn[(size_t)sn2[nt] * CC + c0];
                pv[mt][nt] = *(const float4*)&vn[(size_t)sn2[nt] * CC + c0];
            }
        }

        // ---- gaussian attr rows: a2[r][k] k<64 (k>=50 -> 0); 8 vals/thread ----
        {
            int r = t >> 3, k0 = (t & 7) * 8;
            float dd = dbuf[r];
            __align__(16) u16 tmp[8];
            #pragma unroll
            for (int j = 0; j < 8; ++j) {
                int k = k0 + j;
                float v = 0.0f;
                if (k < GG) { float df = dd - STEP * (float)k; v = __expf(COEF * df * df); }
                tmp[j] = f2bf(v);
            }
            *(float4*)&a2[r * 136 + k0] = *(float4*)&tmp[0];
        }
        __syncthreads();

        // ---- GEMM1^T: [128c x 64k] * [64k x 128r] ----
        f32x4 acc[2][2];
        #pragma unroll
        for (int mt = 0; mt < 2; ++mt)
            #pragma unroll
            for (int nt = 0; nt < 2; ++nt) acc[mt][nt] = zf4;
        #pragma unroll
        for (int s = 0; s < 2; ++s) {
            bf16x8 af[2], bfr[2];
            #pragma unroll
            for (int mt = 0; mt < 2; ++mt)
                af[mt] = *(const bf16x8*)&w1T[(wr * 32 + mt * 16 + tx) * 72 + s * 32 + tg * 8];
            #pragma unroll
            for (int nt = 0; nt < 2; ++nt)
                bfr[nt] = *(const bf16x8*)&a2[(wc * 32 + nt * 16 + tx) * 136 + s * 32 + tg * 8];
            #pragma unroll
            for (int mt = 0; mt < 2; ++mt)
                #pragma unroll
                for (int nt = 0; nt < 2; ++nt)
                    acc[mt][nt] = __builtin_amdgcn_mfma_f32_16x16x32_bf16(af[mt], bfr[nt], acc[mt][nt], 0, 0, 0);
        }
        __syncthreads();   // all G1 reads of a2 done before overwrite
        // ---- ssp(. + b1) -> a2[r][c] (8B writes: 4 consecutive c at fixed r) ----
        #pragma unroll
        for (int mt = 0; mt < 2; ++mt) {
            int c0 = wr * 32 + mt * 16 + tg * 4;
            #pragma unroll
            for (int nt = 0; nt < 2; ++nt) {
                int r = wc * 32 + nt * 16 + tx;
                u16 o0 = f2bf(sspf(acc[mt][nt][0] + b1v[mt * 4 + 0]));
                u16 o1 = f2bf(sspf(acc[mt][nt][1] + b1v[mt * 4 + 1]));
                u16 o2 = f2bf(sspf(acc[mt][nt][2] + b1v[mt * 4 + 2]));
                u16 o3 = f2bf(sspf(acc[mt][nt][3] + b1v[mt * 4 + 3]));
                uint2 pkd = make_uint2((unsigned)o0 | ((unsigned)o1 << 16),
                                       (unsigned)o2 | ((unsigned)o3 << 16));
                *(uint2*)&a2[r * 136 + c0] = pkd;
            }
        }
        __syncthreads();

        // ---- GEMM2^T: e^T = w2^T * act1^T  (K=128) ----
        #pragma unroll
        for (int mt = 0; mt < 2; ++mt)
            #pragma unroll
            for (int nt = 0; nt < 2; ++nt) acc[mt][nt] = zf4;
        #pragma unroll
        for (int s = 0; s < 4; ++s) {
            bf16x8 af[2], bfr[2];
            #pragma unroll
            for (int mt = 0; mt < 2; ++mt)
                af[mt] = *(const bf16x8*)&w2T[(wr * 32 + mt * 16 + tx) * 136 + s * 32 + tg * 8];
            #pragma unroll
            for (int nt = 0; nt < 2; ++nt)
                bfr[nt] = *(const bf16x8*)&a2[(wc * 32 + nt * 16 + tx) * 136 + s * 32 + tg * 8];
            #pragma unroll
            for (int mt = 0; mt < 2; ++mt)
                #pragma unroll
                for (int nt = 0; nt < 2; ++nt)
                    acc[mt][nt] = __builtin_amdgcn_mfma_f32_16x16x32_bf16(af[mt], bfr[nt], acc[mt][nt], 0, 0, 0);
        }
        // ---- e = . + b2 -> e2 (no activation) ----
        #pragma unroll
        for (int mt = 0; mt < 2; ++mt) {
            int c0 = wr * 32 + mt * 16 + tg * 4;
            #pragma unroll
            for (int nt = 0; nt < 2; ++nt) {
                int r = wc * 32 + nt * 16 + tx;
                u16 o0 = f2bf(acc[mt][nt][0] + b2v[mt * 4 + 0]);
                u16 o1 = f2bf(acc[mt][nt][1] + b2v[mt * 4 + 1]);
                u16 o2 = f2bf(acc[mt][nt][2] + b2v[mt * 4 + 2]);
                u16 o3 = f2bf(acc[mt][nt][3] + b2v[mt * 4 + 3]);
                uint2 pkd = make_uint2((unsigned)o0 | ((unsigned)o1 << 16),
                                       (unsigned)o2 | ((unsigned)o3 << 16));
                *(uint2*)&e2[r * 136 + c0] = pkd;
            }
        }
        __syncthreads();

        // ---- GEMM3^T: ep^T = we^T * e^T  (K=128) ----
        #pragma unroll
        for (int mt = 0; mt < 2; ++mt)
            #pragma unroll
            for (int nt = 0; nt < 2; ++nt) acc[mt][nt] = zf4;
        #pragma unroll
        for (int s = 0; s < 4; ++s) {
            bf16x8 af[2], bfr[2];
            #pragma unroll
            for (int mt = 0; mt < 2; ++mt)
                af[mt] = *(const bf16x8*)&weT[(wr * 32 + mt * 16 + tx) * 136 + s * 32 + tg * 8];
            #pragma unroll
            for (int nt = 0; nt < 2; ++nt)
                bfr[nt] = *(const bf16x8*)&e2[(wc * 32 + nt * 16 + tx) * 136 + s * 32 + tg * 8];
            #pragma unroll
            for (int mt = 0; mt < 2; ++mt)
                #pragma unroll
                for (int nt = 0; nt < 2; ++nt)
                    acc[mt][nt] = __builtin_amdgcn_mfma_f32_16x16x32_bf16(af[mt], bfr[nt], acc[mt][nt], 0, 0, 0);
        }
        __syncthreads();   // all G3 reads of e2 done before f32 scatter writes

        // ---- epilogue: ke/ve, per-head logits, w=exp, write w*ve (f32) + w ----
        #pragma unroll
        for (int mt = 0; mt < 2; ++mt) {
            int c0 = wr * 32 + mt * 16 + tg * 4;
            int h = wr * 2 + mt;   // head of this c-range (16 c per head)
            #pragma unroll
            for (int nt = 0; nt < 2; ++nt) {
                float ep0 = acc[mt][nt][0] + bev[mt * 4 + 0];
                float ep1 = acc[mt][nt][1] + bev[mt * 4 + 1];
                float ep2 = acc[mt][nt][2] + bev[mt * 4 + 2];
                float ep3 = acc[mt][nt][3] + bev[mt * 4 + 3];
                float lg = pq[mt][nt].x * (pk[mt][nt].x + ep0)
                         + pq[mt][nt].y * (pk[mt][nt].y + ep1)
                         + pq[mt][nt].z * (pk[mt][nt].z + ep2)
                         + pq[mt][nt].w * (pk[mt][nt].w + ep3);
                lg += __shfl_xor(lg, 16);
                lg += __shfl_xor(lg, 32);          // sum over the 16 c's of the head
                float wgt = __expf(lg * 0.25f);    // scale = 1/sqrt(16); no max needed
                float4 wv;
                wv.x = wgt * (pv[mt][nt].x + ep0); wv.y = wgt * (pv[mt][nt].y + ep1);
                wv.z = wgt * (pv[mt][nt].z + ep2); wv.w = wgt * (pv[mt][nt].w + ep3);
                if (c0 < 64) *(float4*)&a2f[rr2[nt] * 68 + c0] = wv;
                else         *(float4*)&e2f[rr2[nt] * 68 + (c0 - 64)] = wv;
                if (tg == 0) {
                    if (h < 4) a2f[rr2[nt] * 68 + 64 + h] = wgt;
                    else       e2f[rr2[nt] * 68 + 64 + (h - 4)] = wgt;
                }
            }
        }
        __syncthreads();

        // ---- segmented sum, 4 row-chunks x 136 channels = 544 threads ----
        if (t < 544) {
            int ch = t % 136;
            int r0 = (t / 136) * 32;
            float run = 0.0f;
            #pragma unroll 4
            for (int rr = 0; rr < 32; ++rr) {
                int r = r0 + rr;
                float v;
                if (ch < 64)       v = a2f[r * 68 + ch];
                else if (ch < 128) v = e2f[r * 68 + (ch - 64)];
                else if (ch < 132) v = a2f[r * 68 + 64 + (ch - 128)];
                else               v = e2f[r * 68 + 64 + (ch - 132)];
                run += v;
                if (rr == 31 || dls[r + 1] != dls[r]) {
                    int dn = dls[r];
                    if (ch < 128) atomicAdd(&num[(size_t)dn * CC + ch], run);
                    else          atomicAdd(&den[(size_t)dn * HH + (ch - 128)], run);
                    run = 0.0f;
                }
            }
        }
    }
}

// ---------------- output head ----------------
__global__ __launch_bounds__(64) void k_head(
    const float* __restrict__ h,
    const float* __restrict__ w1, const float* __restrict__ b1,
    const float* __restrict__ w2, const float* __restrict__ b2,
    float* __restrict__ out)
{
    const int n = blockIdx.x;
    const int j = threadIdx.x;
    float acc = 0.0f;
    for (int k = 0; k < CC; ++k)
        acc = fmaf(h[(size_t)n * CC + k], w1[k * 64 + j], acc);
    float m = sspf(acc + b1[j]);
    float o = m * w2[j];
    #pragma unroll
    for (int msk = 32; msk > 0; msk >>= 1) o += __shfl_xor(o, msk);
    if (j == 0) out[n] = o + b2[0];
}

extern "C" void kernel_launch(void* const* d_in, const int* in_sizes, int n_in,
                              void* d_out, int out_size, void* d_ws, size_t ws_size,
                              hipStream_t stream)
{
    const int*   z   = (const int*)d_in[0];
    const float* pos = (const float*)d_in[1];
    const int*   ei  = (const int*)d_in[2];
    const float* emb = (const float*)d_in[3];
    const float* w1  = (const float*)d_in[4];
    const float* b1  = (const float*)d_in[5];
    const float* w2  = (const float*)d_in[6];
    const float* b2  = (const float*)d_in[7];
    const float* wq  = (const float*)d_in[8];
    const float* bq  = (const float*)d_in[9];
    const float* wk  = (const float*)d_in[10];
    const float* bk  = (const float*)d_in[11];
    const float* wv  = (const float*)d_in[12];
    const float* bv  = (const float*)d_in[13];
    const float* we  = (const float*)d_in[14];
    const float* be  = (const float*)d_in[15];
    const float* wsk = (const float*)d_in[16];
    const float* bsk = (const float*)d_in[17];
    const float* wl  = (const float*)d_in[18];
    const float* bl  = (const float*)d_in[19];
    const float* wo1 = (const float*)d_in[20];
    const float* bo1 = (const float*)d_in[21];
    const float* wo2 = (const float*)d_in[22];
    const float* bo2 = (const float*)d_in[23];

    char* p = (char*)d_ws;
    auto alloc = [&](size_t bytes) -> void* {
        void* r = (void*)p; p += (bytes + 255) & ~(size_t)255; return r;
    };
    float* h    = (float*)alloc((size_t)NN * CC * 4);
    float* q    = (float*)alloc((size_t)NN * CC * 4);
    float* kk   = (float*)alloc((size_t)NN * CC * 4);
    float* vv   = (float*)alloc((size_t)NN * CC * 4);
    float* skip = (float*)alloc((size_t)NN * CC * 4);
    float* num  = (float*)alloc((size_t)NN * CC * 4);
    float* den  = (float*)alloc((size_t)NN * HH * 4);   // contiguous after num
    u16* w1tg = (u16*)alloc((size_t)LL * 128 * 64 * 2);
    u16* w2tg = (u16*)alloc((size_t)LL * 128 * 128 * 2);
    u16* wetg = (u16*)alloc((size_t)LL * 128 * 128 * 2);
    int* count  = (int*)alloc((size_t)(NN + 1) * 4);
    int* rowptr = (int*)alloc((size_t)(NN + 1) * 4);
    int* cursor = (int*)alloc((size_t)NN * 4);
    int* srcp   = (int*)alloc((size_t)NE * 4);
    int* dstp   = (int*)alloc((size_t)NE * 4);

    k_zero<<<(NN + 255) / 256, 256, 0, stream>>>(count, NN);
    k_hist<<<(NE + 255) / 256, 256, 0, stream>>>(ei, count);
    k_scan<<<1, 1024, 0, stream>>>(count, rowptr, cursor);
    k_scatter<<<(NE + 255) / 256, 256, 0, stream>>>(ei, cursor, srcp, dstp);
    k_hinit<<<(NN * CC + 255) / 256, 256, 0, stream>>>(z, emb, h);
    k_prep<<<(LL * 128 * 128 + 255) / 256, 256, 0, stream>>>(w1, w2, we, w1tg, w2tg, wetg);

    const int gn = (NN + 63) / 64;
    const int nzf = NN * CC + NN * HH;  // num+den are contiguous
    for (int l = 0; l < LL; ++l) {
        k_gemm_qkvs<<<gn, 256, 0, stream>>>(h,
            wq + (size_t)l * CC * CC, wk + (size_t)l * CC * CC,
            wv + (size_t)l * CC * CC, wsk + (size_t)l * CC * CC,
            bq + l * CC, bk + l * CC, bv + l * CC, bsk + l * CC,
            q, kk, vv, skip, NN);
        k_zerof<<<(nzf + 255) / 256, 256, 0, stream>>>(num, nzf);
        k_edge<<<256, 1024, 0, stream>>>(srcp, dstp, pos,
            w1tg + (size_t)l * 128 * 64, w2tg + (size_t)l * 128 * 128, wetg + (size_t)l * 128 * 128,
            b1 + l * FF, b2 + l * FF, be + l * CC,
            q, kk, vv, num, den, NE / TE);
        k_gemm_update<<<gn, 256, 0, stream>>>(num, den, skip,
            wl + (size_t)l * CC * CC, bl + l * CC, h, NN);
    }
    k_head<<<NN, 64, 0, stream>>>(h, wo1, bo1, wo2, bo2, (float*)d_out);
}

// Round 6
// 1429.798 us; speedup vs baseline: 1.2788x; 1.2788x over previous
//
#include <hip/hip_runtime.h>

#define NN 20000
#define NE 640000
#define CC 128
#define HH 8
#define GG 50
#define FF 128
#define LL 3
#define TE 128   // edges per tile in k_edge

typedef unsigned short u16;
typedef __attribute__((ext_vector_type(8))) short bf16x8;   // 8 bf16 = 4 VGPRs
typedef __attribute__((ext_vector_type(4))) float f32x4;

__device__ __forceinline__ u16 f2bf(float f) {
    union { float f; unsigned int i; } x; x.f = f;
    unsigned int r = x.i + 0x7fffu + ((x.i >> 16) & 1u);
    return (u16)(r >> 16);
}
// ShiftedSoftplus: softplus(x)-log2 via HW exp/log; |err| ~1e-7, far below bf16 noise
__device__ __forceinline__ float sspf(float x) {
    return fmaxf(x, 0.0f) + __logf(1.0f + __expf(-fabsf(x))) - 0.69314718055994531f;
}

// ---------------- CSR build (sort edges by dst) ----------------
__global__ void k_zero(int* __restrict__ c, int n) {
    int i = blockIdx.x * 256 + threadIdx.x;
    if (i < n) c[i] = 0;
}

__global__ void k_zerof(float* __restrict__ c, int n) {
    int i = blockIdx.x * 256 + threadIdx.x;
    if (i < n) c[i] = 0.0f;
}

__global__ void k_hist(const int* __restrict__ ei, int* __restrict__ c) {
    int e = blockIdx.x * 256 + threadIdx.x;
    if (e < NE) atomicAdd(&c[ei[NE + e]], 1);
}

__global__ __launch_bounds__(1024) void k_scan(const int* __restrict__ cnt,
                                               int* __restrict__ rowptr,
                                               int* __restrict__ cursor) {
    __shared__ int sums[1024];
    const int t = threadIdx.x;
    int local[20];
    int base = t * 20;
    int s = 0;
    #pragma unroll
    for (int i = 0; i < 20; ++i) {
        int idx = base + i;
        int v = (idx < NN) ? cnt[idx] : 0;
        local[i] = s; s += v;
    }
    sums[t] = s;
    __syncthreads();
    for (int off = 1; off < 1024; off <<= 1) {
        int v = (t >= off) ? sums[t - off] : 0;
        __syncthreads();
        sums[t] += v;
        __syncthreads();
    }
    int excl = (t == 0) ? 0 : sums[t - 1];
    #pragma unroll
    for (int i = 0; i < 20; ++i) {
        int idx = base + i;
        if (idx < NN) { int r = excl + local[i]; rowptr[idx] = r; cursor[idx] = r; }
    }
    if (t == 1023) rowptr[NN] = sums[1023];
}

__global__ void k_scatter(const int* __restrict__ ei, int* __restrict__ cursor,
                          int* __restrict__ srcp, int* __restrict__ dstp) {
    int e = blockIdx.x * 256 + threadIdx.x;
    if (e >= NE) return;
    int s = ei[e], d = ei[NE + e];
    int pp = atomicAdd(&cursor[d], 1);
    srcp[pp] = s; dstp[pp] = d;
}

__global__ void k_hinit(const int* __restrict__ z, const float* __restrict__ emb,
                        float* __restrict__ h) {
    int i = blockIdx.x * 256 + threadIdx.x;
    if (i < NN * CC) h[i] = emb[z[i >> 7] * CC + (i & 127)];
}

// ---------------- weight prep (once per call) ----------------
// w1tg[l][c][k64] (k>=50 zero), bf16 transposed
__global__ void k_prep1(const float* __restrict__ w1, u16* __restrict__ w1tg) {
    int i = blockIdx.x * 256 + threadIdx.x;
    if (i < LL * 128 * 64) {
        int l = i / (128 * 64); int r = i % (128 * 64); int c = r >> 6, k = r & 63;
        float v = (k < GG) ? w1[(l * GG + k) * FF + c] : 0.0f;
        w1tg[i] = f2bf(v);
    }
}

// W23[l][k][cp] = sum_c w2[l][k][c] * we[l][c][cp]; stored transposed bf16 [l][cp][k]
__global__ __launch_bounds__(128) void k_prep23(const float* __restrict__ w2,
                                                const float* __restrict__ we,
                                                u16* __restrict__ w23tg) {
    int l = blockIdx.x >> 7, k = blockIdx.x & 127;
    int cp = threadIdx.x;
    float s = 0.0f;
    for (int c = 0; c < FF; ++c)
        s = fmaf(w2[((size_t)l * FF + k) * FF + c], we[((size_t)l * FF + c) * CC + cp], s);
    w23tg[((size_t)l * CC + cp) * FF + k] = f2bf(s);
}

// b23[l][cp] = be[l][cp] + sum_k b2[l][k] * we[l][k][cp]
__global__ __launch_bounds__(128) void k_prepb(const float* __restrict__ b2,
                                               const float* __restrict__ we,
                                               const float* __restrict__ be,
                                               float* __restrict__ b23g) {
    int l = blockIdx.x;
    int cp = threadIdx.x;
    float s = be[l * CC + cp];
    for (int k = 0; k < FF; ++k)
        s = fmaf(b2[l * FF + k], we[((size_t)l * FF + k) * CC + cp], s);
    b23g[l * CC + cp] = s;
}

// ---------------- fused q/k/v/skip node GEMM: stage h-tile once, 4 weights ------
__global__ __launch_bounds__(256) void k_gemm_qkvs(
    const float* __restrict__ A,
    const float* __restrict__ w0, const float* __restrict__ w1,
    const float* __restrict__ w2, const float* __restrict__ w3,
    const float* __restrict__ c0p, const float* __restrict__ c1p,
    const float* __restrict__ c2p, const float* __restrict__ c3p,
    float* __restrict__ o0, float* __restrict__ o1,
    float* __restrict__ o2, float* __restrict__ o3, int nrows)
{
    __shared__ __align__(16) float aT[128 * 66];
    __shared__ __align__(16) float wT[128 * 36];
    const int t = threadIdx.x;
    const int n0 = blockIdx.x * 64;
    for (int idx = t; idx < 64 * 128; idx += 256) {
        int i = idx >> 7, kx = idx & 127;
        int n = n0 + i;
        aT[kx * 66 + i] = (n < nrows) ? A[(size_t)n * 128 + kx] : 0.0f;
    }
    const int tx = t & 15, ty = t >> 4, e0 = ty * 4;
    const float* WW[4] = { w0, w1, w2, w3 };
    const float* BB[4] = { c0p, c1p, c2p, c3p };
    float*       OO[4] = { o0, o1, o2, o3 };
    #pragma unroll
    for (int m = 0; m < 4; ++m) {
        const float* __restrict__ W = WW[m];
        float acc[4][8];
        #pragma unroll
        for (int i = 0; i < 4; ++i)
        #pragma unroll
        for (int j = 0; j < 8; ++j) acc[i][j] = 0.0f;
        for (int k0 = 0; k0 < 128; k0 += 32) {
            __syncthreads();
            for (int idx = t; idx < 32 * 128; idx += 256) {
                int kx = idx >> 7, c = idx & 127;
                wT[c * 36 + kx] = W[(size_t)(k0 + kx) * 128 + c];
            }
            __syncthreads();
            #pragma unroll 2
            for (int kk = 0; kk < 32; kk += 4) {
                float a[4][4];
                #pragma unroll
                for (int dk = 0; dk < 4; ++dk)
                #pragma unroll
                for (int i = 0; i < 4; ++i) a[dk][i] = aT[(k0 + kk + dk) * 66 + e0 + i];
                #pragma unroll
                for (int j = 0; j < 8; ++j) {
                    const float4 b = *(const float4*)&wT[(tx + 16 * j) * 36 + kk];
                    const float bb[4] = { b.x, b.y, b.z, b.w };
                    #pragma unroll
                    for (int dk = 0; dk < 4; ++dk)
                    #pragma unroll
                    for (int i = 0; i < 4; ++i) acc[i][j] = fmaf(a[dk][i], bb[dk], acc[i][j]);
                }
            }
        }
        #pragma unroll
        for (int j = 0; j < 8; ++j) {
            int c = tx + 16 * j;
            float bb = BB[m][c];
            #pragma unroll
            for (int i = 0; i < 4; ++i) {
                int n = n0 + e0 + i;
                if (n < nrows) OO[m][(size_t)n * 128 + c] = acc[i][j] + bb;
            }
        }
    }
}

// ---------------- fused normalize+skip+ssp -> GEMM(wl) -> h += ------------------
__global__ __launch_bounds__(256) void k_gemm_update(
    const float* __restrict__ num, const float* __restrict__ den,
    const float* __restrict__ skip,
    const float* __restrict__ W, const float* __restrict__ Bias,
    float* __restrict__ h, int nrows)
{
    __shared__ __align__(16) float aT[128 * 66];
    __shared__ __align__(16) float wT[128 * 36];
    const int t = threadIdx.x;
    const int n0 = blockIdx.x * 64;
    for (int idx = t; idx < 64 * 128; idx += 256) {
        int i = idx >> 7, kx = idx & 127;
        int n = n0 + i;
        float val = 0.0f;
        if (n < nrows) {
            float r = num[(size_t)n * 128 + kx] / (den[n * HH + (kx >> 4)] + 1e-16f)
                    + skip[(size_t)n * 128 + kx];
            val = sspf(r);
        }
        aT[kx * 66 + i] = val;
    }
    const int tx = t & 15, ty = t >> 4, e0 = ty * 4;
    float acc[4][8];
    #pragma unroll
    for (int i = 0; i < 4; ++i)
    #pragma unroll
    for (int j = 0; j < 8; ++j) acc[i][j] = 0.0f;
    for (int k0 = 0; k0 < 128; k0 += 32) {
        __syncthreads();
        for (int idx = t; idx < 32 * 128; idx += 256) {
            int kx = idx >> 7, c = idx & 127;
            wT[c * 36 + kx] = W[(size_t)(k0 + kx) * 128 + c];
        }
        __syncthreads();
        #pragma unroll 2
        for (int kk = 0; kk < 32; kk += 4) {
            float a[4][4];
            #pragma unroll
            for (int dk = 0; dk < 4; ++dk)
            #pragma unroll
            for (int i = 0; i < 4; ++i) a[dk][i] = aT[(k0 + kk + dk) * 66 + e0 + i];
            #pragma unroll
            for (int j = 0; j < 8; ++j) {
                const float4 b = *(const float4*)&wT[(tx + 16 * j) * 36 + kk];
                const float bb[4] = { b.x, b.y, b.z, b.w };
                #pragma unroll
                for (int dk = 0; dk < 4; ++dk)
                #pragma unroll
                for (int i = 0; i < 4; ++i) acc[i][j] = fmaf(a[dk][i], bb[dk], acc[i][j]);
            }
        }
    }
    #pragma unroll
    for (int j = 0; j < 8; ++j) {
        int c = tx + 16 * j;
        float bb = Bias[c];
        #pragma unroll
        for (int i = 0; i < 4; ++i) {
            int n = n0 + e0 + i;
            if (n < nrows) h[(size_t)n * 128 + c] += acc[i][j] + bb;
        }
    }
}

// ---------------- persistent MFMA edge pipeline (GEMM2/3 algebraically fused) ----
// 16 waves (1024 thr). Wave w: wr=w>>2 owns c-rows [wr*32,+32), wc=w&3 owns
// edge-cols [wc*32,+32). C^T[c][r] = W^T[c][k] * X^T[k][r], MFMA 16x16x32_bf16.
// attr lives in e2; act1 in a2; ep = act1 @ W23 + b23 (W23 = w2@we precomputed).
__global__ __launch_bounds__(1024, 4) void k_edge(
    const int* __restrict__ srcp, const int* __restrict__ dstp,
    const float* __restrict__ pos,
    const u16* __restrict__ w1tg, const u16* __restrict__ w23tg,
    const float* __restrict__ b1, const float* __restrict__ b23,
    const float* __restrict__ qn, const float* __restrict__ kn, const float* __restrict__ vn,
    float* __restrict__ num, float* __restrict__ den, int ntiles)
{
    __shared__ __align__(16) short w1T[128 * 72];    // [c][k64]  row 144B
    __shared__ __align__(16) short wcT[128 * 136];   // combined W23^T [c][k128]
    __shared__ __align__(16) short a2[128 * 136];    // act1 bf16 / f32 w*v (c<64) + w(h<4)
    __shared__ __align__(16) short e2[128 * 136];    // attr bf16 / f32 w*v (c>=64) + w(h>=4)
    __shared__ float dbuf[128];
    __shared__ int sls[128], dls[128];

    const int t = threadIdx.x;
    const int lane = t & 63;
    const int w = t >> 6;
    const int wr = w >> 2, wc = w & 3;
    const int tx = lane & 15, tg = lane >> 4;

    // ---- stage weights once (bf16, transposed rows contiguous) ----
    for (int idx = t; idx < 128 * 8; idx += 1024) {
        int c = idx >> 3, pp = idx & 7;
        *(float4*)&w1T[c * 72 + pp * 8] = *(const float4*)&w1tg[c * 64 + pp * 8];
    }
    for (int idx = t; idx < 128 * 16; idx += 1024) {
        int c = idx >> 4, pp = idx & 15;
        *(float4*)&wcT[c * 136 + pp * 8] = *(const float4*)&w23tg[c * 128 + pp * 8];
    }
    // per-lane bias registers for the c-rows this lane owns
    float b1v[8], bcv[8];
    #pragma unroll
    for (int mt = 0; mt < 2; ++mt)
        #pragma unroll
        for (int q = 0; q < 4; ++q) {
            int c = wr * 32 + mt * 16 + tg * 4 + q;
            b1v[mt * 4 + q] = b1[c]; bcv[mt * 4 + q] = b23[c];
        }

    float* a2f = (float*)a2;   // [r][68] f32 view
    float* e2f = (float*)e2;

    const float STEP = 10.0f / 49.0f;
    const float COEF = -0.5f / (STEP * STEP);
    const f32x4 zf4 = { 0.0f, 0.0f, 0.0f, 0.0f };

    for (int tile = blockIdx.x; tile < ntiles; tile += gridDim.x) {
        __syncthreads();   // B1: previous tile's walk done (reads a2f/e2f/dls)
        if (t < TE) {
            int s = tile * TE + t;
            int a = srcp[s], b = dstp[s];
            sls[t] = a; dls[t] = b;
            float dx = pos[b * 3 + 0] - pos[a * 3 + 0];
            float dy = pos[b * 3 + 1] - pos[a * 3 + 1];
            float dz = pos[b * 3 + 2] - pos[a * 3 + 2];
            dbuf[t] = sqrtf(dx * dx + dy * dy + dz * dz + 1e-12f);
        }
        __syncthreads();   // B2: dbuf ready
        // ---- gaussian attr rows -> e2[r][k] k<64 (k>=50 -> 0); 8 vals/thread ----
        {
            int r = t >> 3, k0 = (t & 7) * 8;
            float dd = dbuf[r];
            __align__(16) u16 tmp[8];
            #pragma unroll
            for (int j = 0; j < 8; ++j) {
                int k = k0 + j;
                float v = 0.0f;
                if (k < GG) { float df = dd - STEP * (float)k; v = __expf(COEF * df * df); }
                tmp[j] = f2bf(v);
            }
            *(float4*)&e2[r * 136 + k0] = *(float4*)&tmp[0];
        }
        __syncthreads();   // B3: attr ready

        // ---- GEMM1^T: [128c x 64k] * [64k x 128r], attr from e2 ----
        f32x4 acc[2][2];
        #pragma unroll
        for (int mt = 0; mt < 2; ++mt)
            #pragma unroll
            for (int nt = 0; nt < 2; ++nt) acc[mt][nt] = zf4;
        #pragma unroll
        for (int s = 0; s < 2; ++s) {
            bf16x8 af[2], bfr[2];
            #pragma unroll
            for (int mt = 0; mt < 2; ++mt)
                af[mt] = *(const bf16x8*)&w1T[(wr * 32 + mt * 16 + tx) * 72 + s * 32 + tg * 8];
            #pragma unroll
            for (int nt = 0; nt < 2; ++nt)
                bfr[nt] = *(const bf16x8*)&e2[(wc * 32 + nt * 16 + tx) * 136 + s * 32 + tg * 8];
            #pragma unroll
            for (int mt = 0; mt < 2; ++mt)
                #pragma unroll
                for (int nt = 0; nt < 2; ++nt)
                    acc[mt][nt] = __builtin_amdgcn_mfma_f32_16x16x32_bf16(af[mt], bfr[nt], acc[mt][nt], 0, 0, 0);
        }
        // ---- ssp(. + b1) -> a2[r][c]; no barrier needed (writes a2, reads were e2) ----
        #pragma unroll
        for (int mt = 0; mt < 2; ++mt) {
            int c0 = wr * 32 + mt * 16 + tg * 4;
            #pragma unroll
            for (int nt = 0; nt < 2; ++nt) {
                int r = wc * 32 + nt * 16 + tx;
                u16 o0 = f2bf(sspf(acc[mt][nt][0] + b1v[mt * 4 + 0]));
                u16 o1 = f2bf(sspf(acc[mt][nt][1] + b1v[mt * 4 + 1]));
                u16 o2 = f2bf(sspf(acc[mt][nt][2] + b1v[mt * 4 + 2]));
                u16 o3 = f2bf(sspf(acc[mt][nt][3] + b1v[mt * 4 + 3]));
                uint2 pkd = make_uint2((unsigned)o0 | ((unsigned)o1 << 16),
                                       (unsigned)o2 | ((unsigned)o3 << 16));
                *(uint2*)&a2[r * 136 + c0] = pkd;
            }
        }
        __syncthreads();   // B4: act1 ready

        // ---- GEMM23^T: ep^T = W23^T * act1^T  (K=128) ----
        #pragma unroll
        for (int mt = 0; mt < 2; ++mt)
            #pragma unroll
            for (int nt = 0; nt < 2; ++nt) acc[mt][nt] = zf4;
        #pragma unroll
        for (int s = 0; s < 4; ++s) {
            bf16x8 af[2], bfr[2];
            #pragma unroll
            for (int mt = 0; mt < 2; ++mt)
                af[mt] = *(const bf16x8*)&wcT[(wr * 32 + mt * 16 + tx) * 136 + s * 32 + tg * 8];
            #pragma unroll
            for (int nt = 0; nt < 2; ++nt)
                bfr[nt] = *(const bf16x8*)&a2[(wc * 32 + nt * 16 + tx) * 136 + s * 32 + tg * 8];
            #pragma unroll
            for (int mt = 0; mt < 2; ++mt)
                #pragma unroll
                for (int nt = 0; nt < 2; ++nt)
                    acc[mt][nt] = __builtin_amdgcn_mfma_f32_16x16x32_bf16(af[mt], bfr[nt], acc[mt][nt], 0, 0, 0);
        }
        __syncthreads();   // B5: all GEMM23 reads of a2 done before f32 scatter writes

        // ---- epilogue: ke/ve, per-head logits, w=exp, write w*ve (f32) + w ----
        {
            int rr2[2], sn2[2], dn2[2];
            #pragma unroll
            for (int nt = 0; nt < 2; ++nt) {
                rr2[nt] = wc * 32 + nt * 16 + tx;
                sn2[nt] = sls[rr2[nt]];
                dn2[nt] = dls[rr2[nt]];
            }
            #pragma unroll
            for (int mt = 0; mt < 2; ++mt) {
                int c0 = wr * 32 + mt * 16 + tg * 4;
                int h = wr * 2 + mt;   // head of this c-range (16 c per head)
                #pragma unroll
                for (int nt = 0; nt < 2; ++nt) {
                    float4 kv = *(const float4*)&kn[(size_t)sn2[nt] * CC + c0];
                    float4 vv = *(const float4*)&vn[(size_t)sn2[nt] * CC + c0];
                    float4 qv = *(const float4*)&qn[(size_t)dn2[nt] * CC + c0];
                    float ep0 = acc[mt][nt][0] + bcv[mt * 4 + 0];
                    float ep1 = acc[mt][nt][1] + bcv[mt * 4 + 1];
                    float ep2 = acc[mt][nt][2] + bcv[mt * 4 + 2];
                    float ep3 = acc[mt][nt][3] + bcv[mt * 4 + 3];
                    float lg = qv.x * (kv.x + ep0) + qv.y * (kv.y + ep1)
                             + qv.z * (kv.z + ep2) + qv.w * (kv.w + ep3);
                    lg += __shfl_xor(lg, 16);
                    lg += __shfl_xor(lg, 32);          // sum over the 16 c's of the head
                    float wgt = __expf(lg * 0.25f);    // scale = 1/sqrt(16); no max needed
                    float4 wv;
                    wv.x = wgt * (vv.x + ep0); wv.y = wgt * (vv.y + ep1);
                    wv.z = wgt * (vv.z + ep2); wv.w = wgt * (vv.w + ep3);
                    if (c0 < 64) *(float4*)&a2f[rr2[nt] * 68 + c0] = wv;
                    else         *(float4*)&e2f[rr2[nt] * 68 + (c0 - 64)] = wv;
                    if (tg == 0) {
                        if (h < 4) a2f[rr2[nt] * 68 + 64 + h] = wgt;
                        else       e2f[rr2[nt] * 68 + 64 + (h - 4)] = wgt;
                    }
                }
            }
        }
        __syncthreads();   // B6: scatter buffers ready for the walk

        // ---- segmented sum, 4 row-chunks x 136 channels = 544 threads ----
        if (t < 544) {
            int ch = t % 136;
            int r0 = (t / 136) * 32;
            float run = 0.0f;
            #pragma unroll 4
            for (int rr = 0; rr < 32; ++rr) {
                int r = r0 + rr;
                float v;
                if (ch < 64)       v = a2f[r * 68 + ch];
                else if (ch < 128) v = e2f[r * 68 + (ch - 64)];
                else if (ch < 132) v = a2f[r * 68 + 64 + (ch - 128)];
                else               v = e2f[r * 68 + 64 + (ch - 132)];
                run += v;
                if (rr == 31 || dls[r + 1] != dls[r]) {
                    int dn = dls[r];
                    if (ch < 128) atomicAdd(&num[(size_t)dn * CC + ch], run);
                    else          atomicAdd(&den[(size_t)dn * HH + (ch - 128)], run);
                    run = 0.0f;
                }
            }
        }
    }
}

// ---------------- output head ----------------
__global__ __launch_bounds__(64) void k_head(
    const float* __restrict__ h,
    const float* __restrict__ w1, const float* __restrict__ b1,
    const float* __restrict__ w2, const float* __restrict__ b2,
    float* __restrict__ out)
{
    const int n = blockIdx.x;
    const int j = threadIdx.x;
    float acc = 0.0f;
    for (int k = 0; k < CC; ++k)
        acc = fmaf(h[(size_t)n * CC + k], w1[k * 64 + j], acc);
    float m = sspf(acc + b1[j]);
    float o = m * w2[j];
    #pragma unroll
    for (int msk = 32; msk > 0; msk >>= 1) o += __shfl_xor(o, msk);
    if (j == 0) out[n] = o + b2[0];
}

extern "C" void kernel_launch(void* const* d_in, const int* in_sizes, int n_in,
                              void* d_out, int out_size, void* d_ws, size_t ws_size,
                              hipStream_t stream)
{
    const int*   z   = (const int*)d_in[0];
    const float* pos = (const float*)d_in[1];
    const int*   ei  = (const int*)d_in[2];
    const float* emb = (const float*)d_in[3];
    const float* w1  = (const float*)d_in[4];
    const float* b1  = (const float*)d_in[5];
    const float* w2  = (const float*)d_in[6];
    const float* b2  = (const float*)d_in[7];
    const float* wq  = (const float*)d_in[8];
    const float* bq  = (const float*)d_in[9];
    const float* wk  = (const float*)d_in[10];
    const float* bk  = (const float*)d_in[11];
    const float* wv  = (const float*)d_in[12];
    const float* bv  = (const float*)d_in[13];
    const float* we  = (const float*)d_in[14];
    const float* be  = (const float*)d_in[15];
    const float* wsk = (const float*)d_in[16];
    const float* bsk = (const float*)d_in[17];
    const float* wl  = (const float*)d_in[18];
    const float* bl  = (const float*)d_in[19];
    const float* wo1 = (const float*)d_in[20];
    const float* bo1 = (const float*)d_in[21];
    const float* wo2 = (const float*)d_in[22];
    const float* bo2 = (const float*)d_in[23];

    char* p = (char*)d_ws;
    auto alloc = [&](size_t bytes) -> void* {
        void* r = (void*)p; p += (bytes + 255) & ~(size_t)255; return r;
    };
    float* h    = (float*)alloc((size_t)NN * CC * 4);
    float* q    = (float*)alloc((size_t)NN * CC * 4);
    float* kk   = (float*)alloc((size_t)NN * CC * 4);
    float* vv   = (float*)alloc((size_t)NN * CC * 4);
    float* skip = (float*)alloc((size_t)NN * CC * 4);
    float* num  = (float*)alloc((size_t)NN * CC * 4);
    float* den  = (float*)alloc((size_t)NN * HH * 4);   // contiguous after num
    u16* w1tg  = (u16*)alloc((size_t)LL * 128 * 64 * 2);
    u16* w23tg = (u16*)alloc((size_t)LL * 128 * 128 * 2);
    float* b23g = (float*)alloc((size_t)LL * 128 * 4);
    int* count  = (int*)alloc((size_t)(NN + 1) * 4);
    int* rowptr = (int*)alloc((size_t)(NN + 1) * 4);
    int* cursor = (int*)alloc((size_t)NN * 4);
    int* srcp   = (int*)alloc((size_t)NE * 4);
    int* dstp   = (int*)alloc((size_t)NE * 4);

    k_zero<<<(NN + 255) / 256, 256, 0, stream>>>(count, NN);
    k_hist<<<(NE + 255) / 256, 256, 0, stream>>>(ei, count);
    k_scan<<<1, 1024, 0, stream>>>(count, rowptr, cursor);
    k_scatter<<<(NE + 255) / 256, 256, 0, stream>>>(ei, cursor, srcp, dstp);
    k_hinit<<<(NN * CC + 255) / 256, 256, 0, stream>>>(z, emb, h);
    k_prep1<<<(LL * 128 * 64 + 255) / 256, 256, 0, stream>>>(w1, w1tg);
    k_prep23<<<LL * 128, 128, 0, stream>>>(w2, we, w23tg);
    k_prepb<<<LL, 128, 0, stream>>>(b2, we, be, b23g);

    const int gn = (NN + 63) / 64;
    const int nzf = NN * CC + NN * HH;  // num+den are contiguous
    for (int l = 0; l < LL; ++l) {
        k_gemm_qkvs<<<gn, 256, 0, stream>>>(h,
            wq + (size_t)l * CC * CC, wk + (size_t)l * CC * CC,
            wv + (size_t)l * CC * CC, wsk + (size_t)l * CC * CC,
            bq + l * CC, bk + l * CC, bv + l * CC, bsk + l * CC,
            q, kk, vv, skip, NN);
        k_zerof<<<(nzf + 255) / 256, 256, 0, stream>>>(num, nzf);
        k_edge<<<256, 1024, 0, stream>>>(srcp, dstp, pos,
            w1tg + (size_t)l * 128 * 64, w23tg + (size_t)l * 128 * 128,
            b1 + l * FF, b23g + l * CC,
            q, kk, vv, num, den, NE / TE);
        k_gemm_update<<<gn, 256, 0, stream>>>(num, den, skip,
            wl + (size_t)l * CC * CC, bl + l * CC, h, NN);
    }
    k_head<<<NN, 64, 0, stream>>>(h, wo1, bo1, wo2, bo2, (float*)d_out);
}